// Round 10
// baseline (130.082 us; speedup 1.0000x reference)
//
#include <hip/hip_runtime.h>
#include <cstdint>

#define NROWS 262144
#define DDIM 64
#define KCL 512
#define BM 32
#define THREADS 256

typedef __attribute__((ext_vector_type(8))) _Float16 half8;
typedef __attribute__((ext_vector_type(16))) float f32x16;
typedef __attribute__((ext_vector_type(4))) float f32x4;
typedef const __attribute__((address_space(1))) void* gas_ptr;
typedef __attribute__((address_space(3))) void* las_ptr;

__device__ __forceinline__ void g2lds16(const void* g, void* l) {
  // async global->LDS, 16B/lane; LDS dest = wave-uniform base + lane*16
  __builtin_amdgcn_global_load_lds((gas_ptr)g, (las_ptr)l, 16, 0, 0);
}

// Pack (-2*c) to fp16 MFMA fragments, chunk-major, + csq[k] = ||c_k||^2.
// byte addr = T*4096 + kk*1024 + lane*16 ; lane l holds
// (-2C)[col = T*32 + (l&31)][d = kk*16 + (l>>5)*8 + i], i = 0..7.
__global__ void prep_kernel(const float* __restrict__ c,
                            char* __restrict__ bpack,
                            float* __restrict__ csq) {
  __shared__ float sS[256];
  const int T = blockIdx.x;     // tile 0..15
  const int tid = threadIdx.x;  // 0..255
  const int kk = tid >> 6, l = tid & 63;
  const int col = T * 32 + (l & 31);
  const int d0 = kk * 16 + ((l >> 5) << 3);
  const float* cp = c + col * DDIM + d0;
  float4 v0 = *(const float4*)cp;
  float4 v1 = *(const float4*)(cp + 4);
  float xv[8] = {v0.x, v0.y, v0.z, v0.w, v1.x, v1.y, v1.z, v1.w};
  half8 hh;
  float s = 0.f;
#pragma unroll
  for (int i = 0; i < 8; ++i) {
    hh[i] = (_Float16)(-2.f * xv[i]);  // RNE; x2 exact
    s = fmaf(xv[i], xv[i], s);
  }
  *(half8*)(bpack + T * 4096 + kk * 1024 + l * 16) = hh;
  sS[tid] = s;
  __syncthreads();
  if (tid < 32) {
    float t = 0.f;
#pragma unroll
    for (int k2 = 0; k2 < 4; ++k2)
#pragma unroll
      for (int h2 = 0; h2 < 2; ++h2) t += sS[k2 * 64 + h2 * 32 + tid];
    csq[T * 32 + tid] = t;
  }
}

__global__ __launch_bounds__(THREADS, 4) void cluster_kernel(
    const float* __restrict__ xg,
    const char* __restrict__ bpack,   // fp16 (-2c) fragments, 64 KB
    const float* __restrict__ csqg,   // ||c||^2, 2 KB
    float* __restrict__ outg) {
  __shared__ __align__(16) char sB[2][16384];  // B dbuf; reused as transpose buf
  __shared__ __align__(16) float sCsq[KCL];    // 2 KB
  __shared__ __align__(16) float sPart[4][BM]; // per-wave row partials

  const int tid = threadIdx.x;
  const int lane = tid & 63;
  const int wv = tid >> 6;
  const int half = lane >> 5;
  const int l5 = lane & 31;
  const long rowBase = (long)blockIdx.x * BM;

  // ---- issue stage: chunk 0 -> sB[0] (16 KB) and csq -> sCsq (2 KB) ----
#pragma unroll
  for (int i = 0; i < 4; ++i) {
    int p = (i * THREADS + tid) * 16;
    g2lds16(bpack + p, (char*)sB[0] + p);
  }
  if (tid < 128) g2lds16((const char*)csqg + tid * 16, (char*)sCsq + tid * 16);

  // ---- X fragments from global: lane -> row l5, dims kk*16 + half*8 + i ----
  half8 xh[4];
  float xsq1;
  {
    const float* xrow = xg + (rowBase + l5) * DDIM + half * 8;
    float s = 0.f;
#pragma unroll
    for (int kk = 0; kk < 4; ++kk) {
      float4 a = *(const float4*)(xrow + kk * 16);
      float4 b = *(const float4*)(xrow + kk * 16 + 4);
      float v[8] = {a.x, a.y, a.z, a.w, b.x, b.y, b.z, b.w};
#pragma unroll
      for (int i = 0; i < 8; ++i) {
        xh[kk][i] = (_Float16)v[i];
        s = fmaf(v[i], v[i], s);
      }
    }
    s += __shfl_xor(s, 32, 64);  // other half of the row
    xsq1 = 1.f + s;
  }

  __syncthreads();  // chunk0 + csq staged (vmcnt drained per wave)

  // ---- acc init = csq[m]; m = T*32 + (r&3) + 8*(r>>2) + 4*half ----
  f32x16 acc[4];
#pragma unroll
  for (int t = 0; t < 4; ++t) {
    const int T = t * 4 + wv;
#pragma unroll
    for (int g = 0; g < 4; ++g) {
      float4 cs = *(const float4*)&sCsq[T * 32 + 4 * half + 8 * g];  // broadcast
      acc[t][4 * g + 0] = cs.x;
      acc[t][4 * g + 1] = cs.y;
      acc[t][4 * g + 2] = cs.z;
      acc[t][4 * g + 3] = cs.w;
    }
  }

  // ---- 4 chunks x (stage next | 4 MFMA: acc += (-2c) . x) ----
#pragma unroll
  for (int ch = 0; ch < 4; ++ch) {
    if (ch < 3) {
#pragma unroll
      for (int i = 0; i < 4; ++i) {
        int p = (i * THREADS + tid) * 16;
        g2lds16(bpack + (ch + 1) * 16384 + p, (char*)sB[(ch + 1) & 1] + p);
      }
    }
    const char* fb = (const char*)sB[ch & 1] + wv * 4096 + lane * 16;
#pragma unroll
    for (int kk = 0; kk < 4; ++kk) {
      half8 ah = *(const half8*)(fb + kk * 1024);  // A = -2c (m = lane&31)
      acc[ch] = __builtin_amdgcn_mfma_f32_32x32x16_f16(ah, xh[kk], acc[ch], 0, 0, 0);
    }
    if (ch < 3) __syncthreads();
  }

  // ---- q = 1/(1 + xsq + csq - 2 cross) = rcp(acc + xsq1), in place ----
#pragma unroll
  for (int t = 0; t < 4; ++t)
#pragma unroll
    for (int r = 0; r < 16; ++r)
      acc[t][r] = __builtin_amdgcn_rcpf(acc[t][r] + xsq1);

  // ---- row sum: in-register tree + one cross-half shuffle ----
  {
    float s01 = 0.f, s23 = 0.f;
#pragma unroll
    for (int r = 0; r < 16; ++r) {
      s01 += acc[0][r] + acc[1][r];
      s23 += acc[2][r] + acc[3][r];
    }
    float s = s01 + s23;
    s += __shfl_xor(s, 32, 64);
    if (half == 0) sPart[wv][l5] = s;
  }
  __syncthreads();

  const float inv = __builtin_amdgcn_rcpf(
      (sPart[0][l5] + sPart[1][l5]) + (sPart[2][l5] + sPart[3][l5]));

  // ---- scale + LDS transpose (reuse sB, 32 KB) + coalesced store ----
  // Two passes of 16 rows. LDS layout: row r (0..15) at r*2048 bytes,
  // byte-within-row cb XOR-swizzled by ((r&7)<<4) to kill the 2KB-stride
  // bank conflict on the write side.
  char* tb = (char*)sB;
#pragma unroll
  for (int p = 0; p < 2; ++p) {
    __syncthreads();  // sB free (main loop / previous pass reads done)
    if ((l5 >> 4) == p) {
      const int r = l5 & 15;
      const int sw = (r & 7) << 4;
#pragma unroll
      for (int t = 0; t < 4; ++t) {
        const int T = t * 4 + wv;
#pragma unroll
        for (int g = 0; g < 4; ++g) {
          f32x4 v;
          v.x = acc[t][4 * g + 0] * inv;
          v.y = acc[t][4 * g + 1] * inv;
          v.z = acc[t][4 * g + 2] * inv;
          v.w = acc[t][4 * g + 3] * inv;
          const int cb = (T * 32 + 8 * g + 4 * half) * 4;
          *(f32x4*)(tb + r * 2048 + (cb ^ sw)) = v;
        }
      }
    }
    __syncthreads();  // tile ready
    {
      const int r2 = tid >> 4;            // 0..15
      const int sw2 = (r2 & 7) << 4;
      const int cb0 = (tid & 15) * 16;    // 16B chunk within row
      float* orow = outg + (rowBase + p * 16 + r2) * (long)KCL;
#pragma unroll
      for (int g = 0; g < 8; ++g) {
        const int cb = cb0 + g * 256;
        f32x4 v = *(const f32x4*)(tb + r2 * 2048 + (cb ^ sw2));
        *(f32x4*)(orow + (cb >> 2)) = v;  // plain cached store (A/B vs nt)
      }
    }
  }
}

extern "C" void kernel_launch(void* const* d_in, const int* in_sizes, int n_in,
                              void* d_out, int out_size, void* d_ws, size_t ws_size,
                              hipStream_t stream) {
  const float* x = (const float*)d_in[0];
  const float* c = (const float*)d_in[1];
  float* out = (float*)d_out;

  char* bpack = (char*)d_ws;                    // 64 KB fp16 fragments
  float* csq = (float*)((char*)d_ws + 65536);   // 2 KB

  hipLaunchKernelGGL(prep_kernel, dim3(16), dim3(256), 0, stream, c, bpack, csq);
  hipLaunchKernelGGL(cluster_kernel, dim3(NROWS / BM), dim3(THREADS), 0, stream,
                     x, bpack, csq, out);
}

// Round 12
// 107.991 us; speedup vs baseline: 1.2046x; 1.2046x over previous
//
#include <hip/hip_runtime.h>
#include <cstdint>

#define NROWS 262144
#define DDIM 64
#define KCL 512
#define BM 32
#define THREADS 256

typedef __attribute__((ext_vector_type(8))) _Float16 half8;
typedef __attribute__((ext_vector_type(16))) float f32x16;
typedef __attribute__((ext_vector_type(4))) float f32x4;
typedef const __attribute__((address_space(1))) void* gas_ptr;
typedef __attribute__((address_space(3))) void* las_ptr;

__device__ __forceinline__ void g2lds16(const void* g, void* l) {
  // async global->LDS, 16B/lane; LDS dest = wave-uniform base + lane*16
  __builtin_amdgcn_global_load_lds((gas_ptr)g, (las_ptr)l, 16, 0, 0);
}

// Pack (-2*c) to fp16 MFMA fragments, chunk-major, + csq[k] = ||c_k||^2.
// byte addr = T*4096 + kk*1024 + lane*16 ; lane l holds
// (-2C)[col = T*32 + (l&31)][d = kk*16 + (l>>5)*8 + i], i = 0..7.
__global__ void prep_kernel(const float* __restrict__ c,
                            char* __restrict__ bpack,
                            float* __restrict__ csq) {
  __shared__ float sS[256];
  const int T = blockIdx.x;     // tile 0..15
  const int tid = threadIdx.x;  // 0..255
  const int kk = tid >> 6, l = tid & 63;
  const int col = T * 32 + (l & 31);
  const int d0 = kk * 16 + ((l >> 5) << 3);
  const float* cp = c + col * DDIM + d0;
  float4 v0 = *(const float4*)cp;
  float4 v1 = *(const float4*)(cp + 4);
  float xv[8] = {v0.x, v0.y, v0.z, v0.w, v1.x, v1.y, v1.z, v1.w};
  half8 hh;
  float s = 0.f;
#pragma unroll
  for (int i = 0; i < 8; ++i) {
    hh[i] = (_Float16)(-2.f * xv[i]);  // RNE; x2 exact
    s = fmaf(xv[i], xv[i], s);
  }
  *(half8*)(bpack + T * 4096 + kk * 1024 + l * 16) = hh;
  sS[tid] = s;
  __syncthreads();
  if (tid < 32) {
    float t = 0.f;
#pragma unroll
    for (int k2 = 0; k2 < 4; ++k2)
#pragma unroll
      for (int h2 = 0; h2 < 2; ++h2) t += sS[k2 * 64 + h2 * 32 + tid];
    csq[T * 32 + tid] = t;
  }
}

__global__ __launch_bounds__(THREADS, 4) void cluster_kernel(
    const float* __restrict__ xg,
    const char* __restrict__ bpack,   // fp16 (-2c) fragments, 64 KB
    const float* __restrict__ csqg,   // ||c||^2, 2 KB
    float* __restrict__ outg) {
  __shared__ __align__(16) char sB[2][16384];  // B dbuf; reused as transpose buf
  __shared__ __align__(16) float sCsq[KCL];    // 2 KB
  __shared__ __align__(16) float sPart[4][BM]; // per-wave row partials

  const int tid = threadIdx.x;
  const int lane = tid & 63;
  const int wv = tid >> 6;
  const int half = lane >> 5;
  const int l5 = lane & 31;
  const long rowBase = (long)blockIdx.x * BM;

  // ---- issue stage: chunk-0 OWN SLICE -> sB[0]+wv*4096, csq -> sCsq ----
  // Wave wv only ever reads its own 4 KB slice of each chunk (tiles ch*4+wv),
  // so staging is wave-private: no cross-wave barrier needed in the main loop.
  {
    const char* gsrc = bpack + wv * 4096;
    char* ldst = (char*)sB[0] + wv * 4096;
#pragma unroll
    for (int i = 0; i < 4; ++i) {
      int p = (i * 64 + lane) * 16;
      g2lds16(gsrc + p, ldst + p);
    }
  }
  if (tid < 128) g2lds16((const char*)csqg + tid * 16, (char*)sCsq + tid * 16);

  // ---- X fragments from global: lane -> row l5, dims kk*16 + half*8 + i ----
  half8 xh[4];
  float xsq1;
  {
    const float* xrow = xg + (rowBase + l5) * DDIM + half * 8;
    float s = 0.f;
#pragma unroll
    for (int kk = 0; kk < 4; ++kk) {
      float4 a = *(const float4*)(xrow + kk * 16);
      float4 b = *(const float4*)(xrow + kk * 16 + 4);
      float v[8] = {a.x, a.y, a.z, a.w, b.x, b.y, b.z, b.w};
#pragma unroll
      for (int i = 0; i < 8; ++i) {
        xh[kk][i] = (_Float16)v[i];
        s = fmaf(v[i], v[i], s);
      }
    }
    s += __shfl_xor(s, 32, 64);  // other half of the row
    xsq1 = 1.f + s;
  }

  __syncthreads();  // barrier #1: csq visible (also drains chunk0 stage)

  // ---- acc init = csq[m]; m = T*32 + (r&3) + 8*(r>>2) + 4*half ----
  f32x16 acc[4];
#pragma unroll
  for (int t = 0; t < 4; ++t) {
    const int T = t * 4 + wv;
#pragma unroll
    for (int g = 0; g < 4; ++g) {
      float4 cs = *(const float4*)&sCsq[T * 32 + 4 * half + 8 * g];  // broadcast
      acc[t][4 * g + 0] = cs.x;
      acc[t][4 * g + 1] = cs.y;
      acc[t][4 * g + 2] = cs.z;
      acc[t][4 * g + 3] = cs.w;
    }
  }

  // ---- 4 chunks, barrier-free: wave-private dbuf + counted vmcnt ----
  // WAR fix vs round 11: before staging into a buffer, s_waitcnt lgkmcnt(0)
  // retires THIS wave's prior ds_reads of that buffer (they feed the MFMAs
  // anyway), and sched_barrier(0) pins the stage issues below those reads.
#pragma unroll
  for (int ch = 0; ch < 4; ++ch) {
    if (ch < 3) {
      asm volatile("s_waitcnt lgkmcnt(0)" ::: "memory");  // prior reads retired
      __builtin_amdgcn_sched_barrier(0);
      const char* gsrc = bpack + (ch + 1) * 16384 + wv * 4096;
      char* ldst = (char*)sB[(ch + 1) & 1] + wv * 4096;
#pragma unroll
      for (int i = 0; i < 4; ++i) {
        int p = (i * 64 + lane) * 16;
        g2lds16(gsrc + p, ldst + p);
      }
      asm volatile("s_waitcnt vmcnt(4)" ::: "memory");  // chunk ch landed
    } else {
      asm volatile("s_waitcnt vmcnt(0)" ::: "memory");
    }
    __builtin_amdgcn_sched_barrier(0);  // rule #18: pin reads after waitcnt
    const char* fb = (const char*)sB[ch & 1] + wv * 4096 + lane * 16;
#pragma unroll
    for (int kk = 0; kk < 4; ++kk) {
      half8 ah = *(const half8*)(fb + kk * 1024);  // A = -2c (m = lane&31)
      acc[ch] = __builtin_amdgcn_mfma_f32_32x32x16_f16(ah, xh[kk], acc[ch], 0, 0, 0);
    }
  }

  // ---- q = 1/(1 + xsq + csq - 2 cross) = rcp(acc + xsq1), in place ----
#pragma unroll
  for (int t = 0; t < 4; ++t)
#pragma unroll
    for (int r = 0; r < 16; ++r)
      acc[t][r] = __builtin_amdgcn_rcpf(acc[t][r] + xsq1);

  // ---- row sum: in-register tree + one cross-half shuffle ----
  {
    float s01 = 0.f, s23 = 0.f;
#pragma unroll
    for (int r = 0; r < 16; ++r) {
      s01 += acc[0][r] + acc[1][r];
      s23 += acc[2][r] + acc[3][r];
    }
    float s = s01 + s23;
    s += __shfl_xor(s, 32, 64);
    if (half == 0) sPart[wv][l5] = s;
  }
  __syncthreads();  // barrier #2: sPart ready; all waves' LDS reads drained

  const float inv = __builtin_amdgcn_rcpf(
      (sPart[0][l5] + sPart[1][l5]) + (sPart[2][l5] + sPart[3][l5]));

  // ---- scale + LDS transpose (reuse sB, 32 KB) + coalesced nt store ----
  // Two passes of 16 rows. LDS layout: row r (0..15) at r*2048 bytes,
  // byte-within-row cb XOR-swizzled by ((r&7)<<4).
  char* tb = (char*)sB;
#pragma unroll
  for (int p = 0; p < 2; ++p) {
    if (p) __syncthreads();  // pass-0 reads done before pass-1 writes
    if ((l5 >> 4) == p) {
      const int r = l5 & 15;
      const int sw = (r & 7) << 4;
#pragma unroll
      for (int t = 0; t < 4; ++t) {
        const int T = t * 4 + wv;
#pragma unroll
        for (int g = 0; g < 4; ++g) {
          f32x4 v;
          v.x = acc[t][4 * g + 0] * inv;
          v.y = acc[t][4 * g + 1] * inv;
          v.z = acc[t][4 * g + 2] * inv;
          v.w = acc[t][4 * g + 3] * inv;
          const int cb = (T * 32 + 8 * g + 4 * half) * 4;
          *(f32x4*)(tb + r * 2048 + (cb ^ sw)) = v;
        }
      }
    }
    __syncthreads();  // tile ready
    {
      const int r2 = tid >> 4;            // 0..15
      const int sw2 = (r2 & 7) << 4;
      const int cb0 = (tid & 15) * 16;    // 16B chunk within row
      float* orow = outg + (rowBase + p * 16 + r2) * (long)KCL;
#pragma unroll
      for (int g = 0; g < 8; ++g) {
        const int cb = cb0 + g * 256;
        f32x4 v = *(const f32x4*)(tb + r2 * 2048 + (cb ^ sw2));
        __builtin_nontemporal_store(v, (f32x4*)(orow + (cb >> 2)));
      }
    }
  }
}

extern "C" void kernel_launch(void* const* d_in, const int* in_sizes, int n_in,
                              void* d_out, int out_size, void* d_ws, size_t ws_size,
                              hipStream_t stream) {
  const float* x = (const float*)d_in[0];
  const float* c = (const float*)d_in[1];
  float* out = (float*)d_out;

  char* bpack = (char*)d_ws;                    // 64 KB fp16 fragments
  float* csq = (float*)((char*)d_ws + 65536);   // 2 KB

  hipLaunchKernelGGL(prep_kernel, dim3(16), dim3(256), 0, stream, c, bpack, csq);
  hipLaunchKernelGGL(cluster_kernel, dim3(NROWS / BM), dim3(THREADS), 0, stream,
                     x, bpack, csq, out);
}